// Round 8
// baseline (123.173 us; speedup 1.0000x reference)
//
#include <hip/hip_runtime.h>
#include <cstdint>
#include <cstddef>

// MemristorDense: y[b,o] = C * sum_i [ exp2(Ep*L + Wp) - exp2(En*L + Wn) ]
// L[b,i]=log2(2x), E=log2(n), W=log2(kG*|w|+G_MIN), C=0.5*maxw/(G_MAX-G_MIN).
// x>=0 so sign handled by exp2(-inf)=0 at x==0.
// R8: in-block split-K, no global atomics, no out zero-init. 512-thread blocks
// (8 waves = 8 interleaved K-splits), 8 batches/block, LDS reduce (pad 9).

#define B128 128
#define NIN  1024
#define NI   1025
#define NO   512
#define NJ   1024
#define GMIN 1.0e-5f
#define GSPAN (1.0e-3f - 1.0e-5f)

__device__ __forceinline__ float flog2(float x) { return __builtin_amdgcn_logf(x); }
__device__ __forceinline__ float fexp2(float x) { return __builtin_amdgcn_exp2f(x); }

// Kernel 1 (grid 256 x 1024): LT[i][b]=1+log2(x[b][i]), per-block |w| max -> bmax[256].
__global__ __launch_bounds__(1024) void k_prep(
    const float* __restrict__ x,
    const float* __restrict__ wp, const float* __restrict__ wn,
    const float* __restrict__ bp, const float* __restrict__ bn,
    float* __restrict__ LT, float* __restrict__ bmax)
{
    const int tid = blockIdx.x * 1024 + threadIdx.x;   // [0, 262144)

    if (tid < NI * B128) {
        int i = tid >> 7, b = tid & 127;
        float xv = (i < NIN) ? x[b * NIN + i] : 1.0f;
        LT[tid] = 1.0f + flog2(xv);                 // log2(2x); x=0 -> -inf (correct)
    }

    // NIN*NO = 524288 = 2 * 262144 exactly
    float m = fmaxf(fmaxf(__builtin_fabsf(wp[tid]), __builtin_fabsf(wn[tid])),
                    fmaxf(__builtin_fabsf(wp[tid + 262144]), __builtin_fabsf(wn[tid + 262144])));
    if (tid < NO) m = fmaxf(m, fmaxf(__builtin_fabsf(bp[tid]), __builtin_fabsf(bn[tid])));

    __shared__ float red[16];
    #pragma unroll
    for (int off = 32; off > 0; off >>= 1) m = fmaxf(m, __shfl_down(m, off, 64));
    if ((threadIdx.x & 63) == 0) red[threadIdx.x >> 6] = m;
    __syncthreads();
    if (threadIdx.x < 16) {
        m = red[threadIdx.x];
        #pragma unroll
        for (int off = 8; off > 0; off >>= 1) m = fmaxf(m, __shfl_down(m, off, 16));
        if (threadIdx.x == 0) bmax[blockIdx.x] = m;
    }
}

// Kernel 2: grid (8 o-tiles, 16 b-tiles) x 512 = 128... no: grid (8,16) would
// underfill. Grid (8 o-tiles, 16 b-tiles) x 512 threads, 8 batches per block:
// 16*8 = 128 batches. 128 blocks x 8 waves = 1024 waves -> too few. Use
// grid (8, 16, 2): z splits K in half (i parity), combined via LDS? No --
// keep it simple: grid (8,16) x 512, each wave = one K-split s in [0,8),
// i = s, s+8, s+16, ... (128 steps), 8 accp+8 accn regs. 128 blocks = 0.5/CU
// is too few; instead 8 batches/block and 32 b-tiles needs B=256. Final:
// grid (8, 32) x 512, 4 batches/block, 8 splits, 64 i-steps per wave, 1024
// blocks = 4/CU = 4 waves/SIMD.
__global__ __launch_bounds__(512) void k_fused(
    const float* __restrict__ nd,
    const float* __restrict__ wp, const float* __restrict__ wn,
    const float* __restrict__ bp, const float* __restrict__ bn,
    const float* __restrict__ LT, const float* __restrict__ bmax,
    float* __restrict__ out)
{
    const int lane = threadIdx.x & 63;
    const int s    = threadIdx.x >> 6;      // wave id = K-split [0,8)
    const int o    = (blockIdx.x << 6) + lane;
    const int b0   = blockIdx.y << 2;       // 4 batches per block

    // reduce 256 per-block maxima (redundant per wave; L2-hot)
    float m = fmaxf(fmaxf(bmax[lane], bmax[lane + 64]),
                    fmaxf(bmax[lane + 128], bmax[lane + 192]));
    #pragma unroll
    for (int off = 32; off > 0; off >>= 1) m = fmaxf(m, __shfl_down(m, off, 64));
    const float maxw = __shfl(m, 0, 64);
    const float kG = GSPAN / maxw;
    const float C  = 0.5f * maxw / GSPAN;

    float accp[4] = {0.f, 0.f, 0.f, 0.f};
    float accn[4] = {0.f, 0.f, 0.f, 0.f};

    // software pipeline: prefetch one interleaved step (stride 8) ahead
    int i = s;
    float2 nv = *(const float2*)(nd + (size_t)i * NJ + 2 * o);
    float wvp = (i < NIN) ? wp[i * NO + o] : bp[o];
    float wvn = (i < NIN) ? wn[i * NO + o] : bn[o];
    float4 L4 = *(const float4*)(LT + i * B128 + b0);

    while (i < NI) {
        const int ip = (i + 8 < NI) ? i + 8 : i;
        float2 nv_n = *(const float2*)(nd + (size_t)ip * NJ + 2 * o);
        float wp_n = (ip < NIN) ? wp[ip * NO + o] : bp[o];
        float wn_n = (ip < NIN) ? wn[ip * NO + o] : bn[o];
        float4 L4n = *(const float4*)(LT + ip * B128 + b0);

        const float Ep = flog2(nv.x);
        const float En = flog2(nv.y);
        const float Wp = flog2(__builtin_fmaf(kG, __builtin_fabsf(wvp), GMIN));
        const float Wn = flog2(__builtin_fmaf(kG, __builtin_fabsf(wvn), GMIN));

        const float Lv[4] = {L4.x, L4.y, L4.z, L4.w};
        #pragma unroll
        for (int j = 0; j < 4; ++j) {
            accp[j] += fexp2(__builtin_fmaf(Ep, Lv[j], Wp));
            accn[j] += fexp2(__builtin_fmaf(En, Lv[j], Wn));
        }

        nv = nv_n; wvp = wp_n; wvn = wn_n; L4 = L4n;
        i += 8;
    }

    // LDS reduction across the 8 splits. Stride 9 floats -> conflict-free.
    __shared__ float lds[8 * 64 * 9];   // 18 KB
    {
        const int base = (s * 64 + lane) * 9;
        #pragma unroll
        for (int j = 0; j < 4; ++j) { lds[base + j] = accp[j]; lds[base + 4 + j] = accn[j]; }
    }
    __syncthreads();

    if (threadIdx.x < 256) {
        const int l = threadIdx.x & 63;       // o offset
        const int b = threadIdx.x >> 6;       // [0,4)
        float sp = 0.f, sn = 0.f;
        #pragma unroll
        for (int w = 0; w < 8; ++w) {
            const int base = (w * 64 + l) * 9;
            sp += lds[base + b];
            sn += lds[base + 4 + b];
        }
        out[(size_t)(b0 + b) * NO + (blockIdx.x << 6) + l] = C * (sp - sn);
    }
}

extern "C" void kernel_launch(void* const* d_in, const int* in_sizes, int n_in,
                              void* d_out, int out_size, void* d_ws, size_t ws_size,
                              hipStream_t stream)
{
    const float* x  = (const float*)d_in[0];
    const float* wp = (const float*)d_in[1];
    const float* wn = (const float*)d_in[2];
    const float* bp = (const float*)d_in[3];
    const float* bn = (const float*)d_in[4];
    const float* nd = (const float*)d_in[5];
    float* out = (float*)d_out;

    unsigned char* ws = (unsigned char*)d_ws;
    float* bmax = (float*)ws;                 // 256 floats
    float* LT   = (float*)(ws + 4096);        // 1025*128*4 = 524800 B

    k_prep<<<256, 1024, 0, stream>>>(x, wp, wn, bp, bn, LT, bmax);
    k_fused<<<dim3(8, 32), 512, 0, stream>>>(nd, wp, wn, bp, bn, LT, bmax, out);
}

// Round 9
// 91.351 us; speedup vs baseline: 1.3483x; 1.3483x over previous
//
#include <hip/hip_runtime.h>
#include <cstdint>
#include <cstddef>

// MemristorDense: y[b,o] = C * sum_i [ exp2(Ep*L + Wp) - exp2(En*L + Wn) ]
// L[b,i]=log2(2x), E=log2(n), W=log2(kG*|w|+G_MIN), C=0.5*maxw/(G_MAX-G_MIN).
// x>=0 so sign handled by exp2(-inf)=0 at x==0.
// R9: R8 post-mortem showed k_fused latency-bound (1160 cyc/step, VALUBusy 34%).
// Fix: 16 batches/wave (4x fewer steps per unit work, log2 amortized to 12.5%),
// 4 waves/SIMD (512 blocks), K split into 8 chunks, 8-way in-block interleave,
// LDS reduce + 8-way atomicAdd per output.

#define B128 128
#define NIN  1024
#define NI   1025
#define NO   512
#define NJ   1024
#define GMIN 1.0e-5f
#define GSPAN (1.0e-3f - 1.0e-5f)
#define ZCH  8      // K-chunks
#define CHUNK 129   // ceil(1025/8)

__device__ __forceinline__ float flog2(float x) { return __builtin_amdgcn_logf(x); }
__device__ __forceinline__ float fexp2(float x) { return __builtin_amdgcn_exp2f(x); }

// Kernel 1 (grid 256 x 1024): zero out, LT[i][b]=1+log2(x[b][i]), block max -> bmax[256].
__global__ __launch_bounds__(1024) void k_prep(
    const float* __restrict__ x,
    const float* __restrict__ wp, const float* __restrict__ wn,
    const float* __restrict__ bp, const float* __restrict__ bn,
    float* __restrict__ LT, float* __restrict__ bmax, float* __restrict__ out)
{
    const int tid = blockIdx.x * 1024 + threadIdx.x;   // [0, 262144)

    if (tid < B128 * NO) out[tid] = 0.0f;

    if (tid < NI * B128) {
        int i = tid >> 7, b = tid & 127;
        float xv = (i < NIN) ? x[b * NIN + i] : 1.0f;
        LT[tid] = 1.0f + flog2(xv);                 // log2(2x); x=0 -> -inf (correct)
    }

    // NIN*NO = 524288 = 2 * 262144 exactly
    float m = fmaxf(fmaxf(__builtin_fabsf(wp[tid]), __builtin_fabsf(wn[tid])),
                    fmaxf(__builtin_fabsf(wp[tid + 262144]), __builtin_fabsf(wn[tid + 262144])));
    if (tid < NO) m = fmaxf(m, fmaxf(__builtin_fabsf(bp[tid]), __builtin_fabsf(bn[tid])));

    __shared__ float red[16];
    #pragma unroll
    for (int off = 32; off > 0; off >>= 1) m = fmaxf(m, __shfl_down(m, off, 64));
    if ((threadIdx.x & 63) == 0) red[threadIdx.x >> 6] = m;
    __syncthreads();
    if (threadIdx.x < 16) {
        m = red[threadIdx.x];
        #pragma unroll
        for (int off = 8; off > 0; off >>= 1) m = fmaxf(m, __shfl_down(m, off, 16));
        if (threadIdx.x == 0) bmax[blockIdx.x] = m;
    }
}

// Kernel 2: grid (8 o-tiles, 8 b-tiles, 8 K-chunks) x 512 threads (8 waves).
// 512 blocks = 2/CU (66 KB LDS), 4096 waves = 4/SIMD. Wave s covers chunk i's
// with stride 8 (~16 steps); 16 batches per wave; per step: 4 log2 + 32 exp2.
// LDS reduce across 8 waves, then 8-way atomicAdd into out.
__global__ __launch_bounds__(512) void k_main(
    const float* __restrict__ nd,
    const float* __restrict__ wp, const float* __restrict__ wn,
    const float* __restrict__ bp, const float* __restrict__ bn,
    const float* __restrict__ LT, const float* __restrict__ bmax,
    float* __restrict__ out)
{
    const int lane = threadIdx.x & 63;
    const int s    = threadIdx.x >> 6;      // wave id [0,8)
    const int o    = (blockIdx.x << 6) + lane;
    const int b0   = blockIdx.y << 4;       // 16 batches per block

    // reduce 256 per-block maxima (redundant per wave; L2-hot)
    float m = fmaxf(fmaxf(bmax[lane], bmax[lane + 64]),
                    fmaxf(bmax[lane + 128], bmax[lane + 192]));
    #pragma unroll
    for (int off = 32; off > 0; off >>= 1) m = fmaxf(m, __shfl_down(m, off, 64));
    const float maxw = __shfl(m, 0, 64);
    const float kG = GSPAN / maxw;
    const float C  = 0.5f * maxw / GSPAN;

    const int i0 = blockIdx.z * CHUNK;
    int i1 = i0 + CHUNK; if (i1 > NI) i1 = NI;   // every chunk has >= 122 i's

    float accp[16], accn[16];
    #pragma unroll
    for (int k = 0; k < 16; ++k) { accp[k] = 0.0f; accn[k] = 0.0f; }

    // software pipeline: prefetch one stride-8 step ahead
    int i = i0 + s;                                // i0+s < i1 always (chunk >= 122)
    float2 nv = *(const float2*)(nd + (size_t)i * NJ + 2 * o);
    float wvp = (i < NIN) ? wp[i * NO + o] : bp[o];
    float wvn = (i < NIN) ? wn[i * NO + o] : bn[o];
    float4 La = *(const float4*)(LT + i * B128 + b0);
    float4 Lb = *(const float4*)(LT + i * B128 + b0 + 4);
    float4 Lc = *(const float4*)(LT + i * B128 + b0 + 8);
    float4 Ld = *(const float4*)(LT + i * B128 + b0 + 12);

    while (i < i1) {
        const int ip = (i + 8 < i1) ? i + 8 : i;
        float2 nv_n = *(const float2*)(nd + (size_t)ip * NJ + 2 * o);
        float wp_n = (ip < NIN) ? wp[ip * NO + o] : bp[o];
        float wn_n = (ip < NIN) ? wn[ip * NO + o] : bn[o];
        float4 Lan = *(const float4*)(LT + ip * B128 + b0);
        float4 Lbn = *(const float4*)(LT + ip * B128 + b0 + 4);
        float4 Lcn = *(const float4*)(LT + ip * B128 + b0 + 8);
        float4 Ldn = *(const float4*)(LT + ip * B128 + b0 + 12);

        const float Ep = flog2(nv.x);
        const float En = flog2(nv.y);
        const float Wp = flog2(__builtin_fmaf(kG, __builtin_fabsf(wvp), GMIN));
        const float Wn = flog2(__builtin_fmaf(kG, __builtin_fabsf(wvn), GMIN));

        const float Lv[16] = {La.x, La.y, La.z, La.w, Lb.x, Lb.y, Lb.z, Lb.w,
                              Lc.x, Lc.y, Lc.z, Lc.w, Ld.x, Ld.y, Ld.z, Ld.w};
        #pragma unroll
        for (int j = 0; j < 16; ++j) {
            accp[j] += fexp2(__builtin_fmaf(Ep, Lv[j], Wp));
            accn[j] += fexp2(__builtin_fmaf(En, Lv[j], Wn));
        }

        nv = nv_n; wvp = wp_n; wvn = wn_n;
        La = Lan; Lb = Lbn; Lc = Lcn; Ld = Ldn;
        i += 8;
    }

    // LDS reduce across the 8 waves. Row stride 33 floats -> conflict-free.
    __shared__ float lds[8 * 64 * 33];   // 67584 B
    {
        const int base = (s * 64 + lane) * 33;
        #pragma unroll
        for (int j = 0; j < 16; ++j) { lds[base + j] = accp[j]; lds[base + 16 + j] = accn[j]; }
    }
    __syncthreads();

    {
        const int l = threadIdx.x & 63;
        #pragma unroll
        for (int r = 0; r < 2; ++r) {
            const int bb = (threadIdx.x >> 6) + (r << 3);   // [0,16)
            float sum = 0.0f;
            #pragma unroll
            for (int w = 0; w < 8; ++w) {
                const int base = (w * 64 + l) * 33;
                sum += lds[base + bb] - lds[base + 16 + bb];
            }
            unsafeAtomicAdd(out + (size_t)(b0 + bb) * NO + (blockIdx.x << 6) + l, C * sum);
        }
    }
}

extern "C" void kernel_launch(void* const* d_in, const int* in_sizes, int n_in,
                              void* d_out, int out_size, void* d_ws, size_t ws_size,
                              hipStream_t stream)
{
    const float* x  = (const float*)d_in[0];
    const float* wp = (const float*)d_in[1];
    const float* wn = (const float*)d_in[2];
    const float* bp = (const float*)d_in[3];
    const float* bn = (const float*)d_in[4];
    const float* nd = (const float*)d_in[5];
    float* out = (float*)d_out;

    unsigned char* ws = (unsigned char*)d_ws;
    float* bmax = (float*)ws;                 // 256 floats
    float* LT   = (float*)(ws + 4096);        // 1025*128*4 = 524800 B

    k_prep<<<256, 1024, 0, stream>>>(x, wp, wn, bp, bn, LT, bmax, out);
    k_main<<<dim3(8, 8, ZCH), 512, 0, stream>>>(nd, wp, wn, bp, bn, LT, bmax, out);
}

// Round 11
// 88.344 us; speedup vs baseline: 1.3942x; 1.0340x over previous
//
#include <hip/hip_runtime.h>
#include <cstdint>
#include <cstddef>

// MemristorDense: y[b,o] = C * sum_i [ exp2(Ep*L + Wp) - exp2(En*L + Wn) ]
// L[b,i]=log2(2x), E=log2(n), W=log2(kG*|w|+G_MIN), C=0.5*maxw/(G_MAX-G_MIN).
// R11: revert to R9's proven structure (R10's launch_bounds cap + diff-acc
// failed post-timing). Bias row i=1024 folded out exactly: L=1 -> term =
// n*g (pure mul), added once in reduce by z==0 blocks. Hot loop is i in
// [0,1024): no bounds selects, no bp/bn, constant power-of-2 pointer bumps.

#define B128 128
#define NIN  1024
#define NI   1025
#define NO   512
#define NJ   1024
#define GMIN 1.0e-5f
#define GSPAN (1.0e-3f - 1.0e-5f)
#define ZCH  8      // K-chunks over [0,1024)
#define CHUNK 128

__device__ __forceinline__ float flog2(float x) { return __builtin_amdgcn_logf(x); }
__device__ __forceinline__ float fexp2(float x) { return __builtin_amdgcn_exp2f(x); }

// Kernel 1 (grid 256 x 1024): zero out, LT[i][b]=1+log2(x[b][i]), block max -> bmax[256].
__global__ __launch_bounds__(1024) void k_prep(
    const float* __restrict__ x,
    const float* __restrict__ wp, const float* __restrict__ wn,
    const float* __restrict__ bp, const float* __restrict__ bn,
    float* __restrict__ LT, float* __restrict__ bmax, float* __restrict__ out)
{
    const int tid = blockIdx.x * 1024 + threadIdx.x;   // [0, 262144)

    if (tid < B128 * NO) out[tid] = 0.0f;

    if (tid < NI * B128) {
        int i = tid >> 7, b = tid & 127;
        float xv = (i < NIN) ? x[b * NIN + i] : 1.0f;
        LT[tid] = 1.0f + flog2(xv);                 // log2(2x); x=0 -> -inf (correct)
    }

    // NIN*NO = 524288 = 2 * 262144 exactly
    float m = fmaxf(fmaxf(__builtin_fabsf(wp[tid]), __builtin_fabsf(wn[tid])),
                    fmaxf(__builtin_fabsf(wp[tid + 262144]), __builtin_fabsf(wn[tid + 262144])));
    if (tid < NO) m = fmaxf(m, fmaxf(__builtin_fabsf(bp[tid]), __builtin_fabsf(bn[tid])));

    __shared__ float red[16];
    #pragma unroll
    for (int off = 32; off > 0; off >>= 1) m = fmaxf(m, __shfl_down(m, off, 64));
    if ((threadIdx.x & 63) == 0) red[threadIdx.x >> 6] = m;
    __syncthreads();
    if (threadIdx.x < 16) {
        m = red[threadIdx.x];
        #pragma unroll
        for (int off = 8; off > 0; off >>= 1) m = fmaxf(m, __shfl_down(m, off, 16));
        if (threadIdx.x == 0) bmax[blockIdx.x] = m;
    }
}

// Kernel 2: grid (8 o-tiles, 8 b-tiles, 8 K-chunks) x 512 threads (8 waves).
// 512 blocks = 2/CU (67.5 KB LDS) = 4 waves/SIMD. Wave s handles
// i = z*128 + s + 8k, k in [0,16) -- exactly 16 steps, no bounds checks.
// 16 batches/wave; per step: 4 log2 + 32 exp2. LDS reduce across 8 waves,
// bias (i=1024, pure mul) added by z==0 blocks, atomicAdd into out.
__global__ __launch_bounds__(512) void k_main(
    const float* __restrict__ nd,
    const float* __restrict__ wp, const float* __restrict__ wn,
    const float* __restrict__ bp, const float* __restrict__ bn,
    const float* __restrict__ LT, const float* __restrict__ bmax,
    float* __restrict__ out)
{
    const int lane = threadIdx.x & 63;
    const int s    = threadIdx.x >> 6;      // wave id [0,8)
    const int o    = (blockIdx.x << 6) + lane;
    const int b0   = blockIdx.y << 4;       // 16 batches per block

    // reduce 256 per-block maxima (redundant per wave; L2-hot)
    float m = fmaxf(fmaxf(bmax[lane], bmax[lane + 64]),
                    fmaxf(bmax[lane + 128], bmax[lane + 192]));
    #pragma unroll
    for (int off = 32; off > 0; off >>= 1) m = fmaxf(m, __shfl_down(m, off, 64));
    const float maxw = __shfl(m, 0, 64);
    const float kG = GSPAN / maxw;
    const float C  = 0.5f * maxw / GSPAN;

    const int i0 = blockIdx.z * CHUNK + s;   // this wave's first i

    const float* pnd = nd + (size_t)i0 * NJ + 2 * o;
    const float* pwp = wp + (size_t)i0 * NO + o;
    const float* pwn = wn + (size_t)i0 * NO + o;
    const float* pL  = LT + (size_t)i0 * B128 + b0;

    float accp[16], accn[16];
    #pragma unroll
    for (int k = 0; k < 16; ++k) { accp[k] = 0.0f; accn[k] = 0.0f; }

    // prologue loads for k=0
    float2 nv = *(const float2*)pnd;
    float wvp = *pwp;
    float wvn = *pwn;
    float4 La = *(const float4*)(pL);
    float4 Lb = *(const float4*)(pL + 4);
    float4 Lc = *(const float4*)(pL + 8);
    float4 Ld = *(const float4*)(pL + 12);

    #pragma unroll 3
    for (int k = 0; k < 15; ++k) {
        pnd += 8 * NJ; pwp += 8 * NO; pwn += 8 * NO; pL += 8 * B128;
        float2 nv_n = *(const float2*)pnd;
        float wp_n = *pwp;
        float wn_n = *pwn;
        float4 Lan = *(const float4*)(pL);
        float4 Lbn = *(const float4*)(pL + 4);
        float4 Lcn = *(const float4*)(pL + 8);
        float4 Ldn = *(const float4*)(pL + 12);

        const float Ep = flog2(nv.x);
        const float En = flog2(nv.y);
        const float Wp = flog2(__builtin_fmaf(kG, __builtin_fabsf(wvp), GMIN));
        const float Wn = flog2(__builtin_fmaf(kG, __builtin_fabsf(wvn), GMIN));

        const float Lv[16] = {La.x, La.y, La.z, La.w, Lb.x, Lb.y, Lb.z, Lb.w,
                              Lc.x, Lc.y, Lc.z, Lc.w, Ld.x, Ld.y, Ld.z, Ld.w};
        #pragma unroll
        for (int j = 0; j < 16; ++j) {
            accp[j] += fexp2(__builtin_fmaf(Ep, Lv[j], Wp));
            accn[j] += fexp2(__builtin_fmaf(En, Lv[j], Wn));
        }

        nv = nv_n; wvp = wp_n; wvn = wn_n;
        La = Lan; Lb = Lbn; Lc = Lcn; Ld = Ldn;
    }

    // last step (k=15), no prefetch
    {
        const float Ep = flog2(nv.x);
        const float En = flog2(nv.y);
        const float Wp = flog2(__builtin_fmaf(kG, __builtin_fabsf(wvp), GMIN));
        const float Wn = flog2(__builtin_fmaf(kG, __builtin_fabsf(wvn), GMIN));
        const float Lv[16] = {La.x, La.y, La.z, La.w, Lb.x, Lb.y, Lb.z, Lb.w,
                              Lc.x, Lc.y, Lc.z, Lc.w, Ld.x, Ld.y, Ld.z, Ld.w};
        #pragma unroll
        for (int j = 0; j < 16; ++j) {
            accp[j] += fexp2(__builtin_fmaf(Ep, Lv[j], Wp));
            accn[j] += fexp2(__builtin_fmaf(En, Lv[j], Wn));
        }
    }

    // LDS reduce across the 8 waves. Row stride 33 floats -> conflict-free.
    __shared__ float lds[8 * 64 * 33];   // 67584 B
    {
        const int base = (s * 64 + lane) * 33;
        #pragma unroll
        for (int j = 0; j < 16; ++j) { lds[base + j] = accp[j]; lds[base + 16 + j] = accn[j]; }
    }
    __syncthreads();

    // bias row (i=1024): L=1 -> term = exp2(E+W) = n * g. Batch-independent;
    // added once per output by the z==0 blocks. Pure multiplies, no exp2.
    float bias = 0.0f;
    if (blockIdx.z == 0) {
        const float2 nb = *(const float2*)(nd + (size_t)NIN * NJ + 2 * o);
        const float gp = __builtin_fmaf(kG, __builtin_fabsf(bp[o]), GMIN);
        const float gn = __builtin_fmaf(kG, __builtin_fabsf(bn[o]), GMIN);
        bias = nb.x * gp - nb.y * gn;
    }

    {
        const int l = threadIdx.x & 63;
        #pragma unroll
        for (int r = 0; r < 2; ++r) {
            const int bb = (threadIdx.x >> 6) + (r << 3);   // [0,16)
            float sum = bias;
            #pragma unroll
            for (int w = 0; w < 8; ++w) {
                const int base = (w * 64 + l) * 33;
                sum += lds[base + bb] - lds[base + 16 + bb];
            }
            unsafeAtomicAdd(out + (size_t)(b0 + bb) * NO + (blockIdx.x << 6) + l, C * sum);
        }
    }
}

extern "C" void kernel_launch(void* const* d_in, const int* in_sizes, int n_in,
                              void* d_out, int out_size, void* d_ws, size_t ws_size,
                              hipStream_t stream)
{
    const float* x  = (const float*)d_in[0];
    const float* wp = (const float*)d_in[1];
    const float* wn = (const float*)d_in[2];
    const float* bp = (const float*)d_in[3];
    const float* bn = (const float*)d_in[4];
    const float* nd = (const float*)d_in[5];
    float* out = (float*)d_out;

    unsigned char* ws = (unsigned char*)d_ws;
    float* bmax = (float*)ws;                 // 256 floats
    float* LT   = (float*)(ws + 4096);        // 1025*128*4 = 524800 B

    k_prep<<<256, 1024, 0, stream>>>(x, wp, wn, bp, bn, LT, bmax, out);
    k_main<<<dim3(8, 8, ZCH), 512, 0, stream>>>(nd, wp, wn, bp, bn, LT, bmax, out);
}